// Round 11
// baseline (34.198 us; speedup 1.0000x reference)
//
#include <hip/hip_runtime.h>
#include <stdint.h>

#define N_TOK 4096
#define D_IN  64
#define NF    32
#define NH    4
#define OUTW  (NH * NF)        // 128
#define NT    8
#define CHUNK 128              // n per chunk (4 k-steps of 32)
#define BT    64               // rows per block (4 rowgroups of 16)

typedef float        f32x4  __attribute__((ext_vector_type(4)));
typedef unsigned int uint4v __attribute__((ext_vector_type(4)));
typedef __bf16       bf16x8 __attribute__((ext_vector_type(8)));

union Frag { uint4v u; bf16x8 v; };

static __device__ __forceinline__ unsigned short f2bf_rne(float x) {
  unsigned u = __float_as_uint(x);
  u += 0x7fffu + ((u >> 16) & 1u);
  return (unsigned short)(u >> 16);
}

// ---------- Kernel 1 (proven, unchanged): PB = [WG2 | ED] fragment-packed ----
// PB 16-B slot ((t*9 + set)*64 + gq*16 + col): t = n>>5, gq = (n>>3)&3,
// set<8: h*2+fhalf, col = f&15; set==8: den-frag (col<4 -> ED[n][col], else 0).
__global__ __launch_bounds__(128) void prep_kernel(
    const float* __restrict__ G, const float* __restrict__ W,
    const float* __restrict__ bias, const float* __restrict__ a_dst,
    unsigned short* __restrict__ PB) {
  __shared__ float gs[NT * D_IN];
  const int tid = threadIdx.x;
  const int n0  = blockIdx.x * NT;
  {
    const float4* src = (const float4*)(G + (size_t)n0 * D_IN);
    float4* dst = (float4*)gs;
    dst[tid] = src[tid];
  }
  __syncthreads();
  const int h = tid >> 5, f = tid & 31;
  float acc[NT];
  const float bb = bias[h * NF + f];
#pragma unroll
  for (int k = 0; k < NT; ++k) acc[k] = bb;
#pragma unroll
  for (int i = 0; i < D_IN; ++i) {
    const float wv = W[(h * D_IN + i) * NF + f];
#pragma unroll
    for (int k = 0; k < NT; ++k) acc[k] = fmaf(gs[k * D_IN + i], wv, acc[k]);
  }
  const float ad = a_dst[h * NF + f];
  float ev[NT];
#pragma unroll
  for (int k = 0; k < NT; ++k) {
    float s = acc[k] * ad;
    s += __shfl_xor(s, 1);  s += __shfl_xor(s, 2);  s += __shfl_xor(s, 4);
    s += __shfl_xor(s, 8);  s += __shfl_xor(s, 16);
    ev[k] = __expf(s);
  }
  const int t   = n0 >> 5;
  const int gq  = (n0 >> 3) & 3;
  const int set = (h << 1) | (f >> 4);
  const int col = f & 15;
  union { uint4 u4; unsigned short us[8]; } pk;
#pragma unroll
  for (int k = 0; k < NT; ++k) pk.us[k] = f2bf_rne(acc[k] * ev[k]);
  *(uint4*)(PB + (size_t)((((t * 9 + set) << 6) + (gq << 4) + col)) * 8) = pk.u4;
  if (f == 0) {
    union { uint4 u4; unsigned short us[8]; } pe;
#pragma unroll
    for (int k = 0; k < NT; ++k) pe.us[k] = f2bf_rne(ev[k]);
    *(uint4*)(PB + (size_t)((((t * 9 + 8) << 6) + (gq << 4) + h)) * 8) = pe.u4;
  }
  if (h == 0 && f >= 4 && f < 16) {
    uint4 z; z.x = 0u; z.y = 0u; z.z = 0u; z.w = 0u;
    *(uint4*)(PB + (size_t)((((t * 9 + 8) << 6) + (gq << 4) + f)) * 8) = z;
  }
}

// ---------- Kernel 2: BT=64, single-buffered den (VGPR diet), NS tiers ------
// grid = (4096/64)*NS, 512 thr (8 waves = sets). Wave 0 also computes den via
// single-buffered den-frags loaded per-iter: w0 queue vmcnt(12) pre-exp /
// vmcnt(8) post-barrier; w>0 queue vmcnt(8) pre-exp.
template <int NS>
__global__ __launch_bounds__(512) void attn_kernel(
    const float* __restrict__ A, const unsigned short* __restrict__ PB,
    float* __restrict__ op, float* __restrict__ dp, float* __restrict__ out) {
  constexpr int NHALF  = N_TOK / NS;
  constexpr int NIT    = NHALF / CHUNK;
  constexpr int RINGSZ = BT * CHUNK * 2;               // 16384 B
  __shared__ __align__(16) unsigned short ring[3 * BT * CHUNK];  // 48 KB
  __shared__ float denLds[BT * NH];                    // 1 KB
  char* ringb = (char*)ring;

  const int tid  = threadIdx.x;
  const int lane = tid & 63;
  const int w    = tid >> 6;
  const int bid  = blockIdx.x;
  const int s    = bid & (NS - 1);
  const int b0   = (bid / NS) * BT;

  // staging coords: 512 thr = 64 rows x 8 col-groups of 16
  const int srow = tid >> 3, tp = tid & 7;
  const float* abase = A + (size_t)(b0 + srow) * N_TOK + s * NHALF + tp * 16;
  // two swizzled 16-B slots (granules 2tp, 2tp+1)
  const int wb0 = srow * 256 + (((tp * 2    ) ^ (srow & 15)) << 4);
  const int wb1 = srow * 256 + (((tp * 2 + 1) ^ (srow & 15)) << 4);

  // MFMA frag coords
  const int rowm = lane & 15, g = lane >> 4;
  const char* pbb  = (const char*)PB + (size_t)s * (NHALF / 32) * 9216;
  const char* pown = pbb + (((w << 6) + lane) << 4);
  const char* pden = pbb + (((8 << 6) + lane) << 4);

  f32x4 acc0  = {0.f, 0.f, 0.f, 0.f}, acc1  = {0.f, 0.f, 0.f, 0.f};
  f32x4 acc2  = {0.f, 0.f, 0.f, 0.f}, acc3  = {0.f, 0.f, 0.f, 0.f};
  f32x4 accd0 = {0.f, 0.f, 0.f, 0.f}, accd1 = {0.f, 0.f, 0.f, 0.f};
  f32x4 accd2 = {0.f, 0.f, 0.f, 0.f}, accd3 = {0.f, 0.f, 0.f, 0.f};
  f32x4 aXa, aXb, aXc, aXd, aYa, aYb, aYc, aYd;
  Frag bo0, bo1, bo2, bo3;           // own frags, buffer A
  Frag co0, co1, co2, co3;           // own frags, buffer B
  Frag bd0, bd1, bd2, bd3;           // den frags, single-buffered (w0 only use)
  int mR = 0, mW = 1;

#define LOADA4(d0, d1, d2, d3, cc) do {                                        \
    const float* ap_ = abase + (size_t)(cc) * CHUNK;                           \
    asm volatile("global_load_dwordx4 %0, %1, off"                            \
                 : "=v"(d0) : "v"(ap_) : "memory");                            \
    asm volatile("global_load_dwordx4 %0, %1, off"                            \
                 : "=v"(d1) : "v"(ap_ + 4) : "memory");                        \
    asm volatile("global_load_dwordx4 %0, %1, off"                            \
                 : "=v"(d2) : "v"(ap_ + 8) : "memory");                        \
    asm volatile("global_load_dwordx4 %0, %1, off"                            \
                 : "=v"(d3) : "v"(ap_ + 12) : "memory");                       \
  } while (0)
#define LOADBO(fr, cc, kk)                                                     \
  asm volatile("global_load_dwordx4 %0, %1, off"                              \
               : "=v"(fr.u)                                                    \
               : "v"(pown + (size_t)((cc) * 4 + (kk)) * 9216) : "memory")
#define LOADBD(fr, cc, kk)                                                     \
  asm volatile("global_load_dwordx4 %0, %1, off"                              \
               : "=v"(fr.u)                                                    \
               : "v"(pden + (size_t)((cc) * 4 + (kk)) * 9216) : "memory")

#define EXPP(AV0, AV1, AV2, AV3, mw) do {                                      \
    float x0 = __expf(-AV0[0]), x1 = __expf(-AV0[1]);                          \
    float x2 = __expf(-AV0[2]), x3 = __expf(-AV0[3]);                          \
    float x4 = __expf(-AV1[0]), x5 = __expf(-AV1[1]);                          \
    float x6 = __expf(-AV1[2]), x7 = __expf(-AV1[3]);                          \
    float y0 = __expf(-AV2[0]), y1 = __expf(-AV2[1]);                          \
    float y2 = __expf(-AV2[2]), y3 = __expf(-AV2[3]);                          \
    float y4 = __expf(-AV3[0]), y5 = __expf(-AV3[1]);                          \
    float y6 = __expf(-AV3[2]), y7 = __expf(-AV3[3]);                          \
    uint4v t_, u_;                                                             \
    t_[0] = __builtin_amdgcn_perm(__float_as_uint(x1), __float_as_uint(x0), 0x07060302u); \
    t_[1] = __builtin_amdgcn_perm(__float_as_uint(x3), __float_as_uint(x2), 0x07060302u); \
    t_[2] = __builtin_amdgcn_perm(__float_as_uint(x5), __float_as_uint(x4), 0x07060302u); \
    t_[3] = __builtin_amdgcn_perm(__float_as_uint(x7), __float_as_uint(x6), 0x07060302u); \
    u_[0] = __builtin_amdgcn_perm(__float_as_uint(y1), __float_as_uint(y0), 0x07060302u); \
    u_[1] = __builtin_amdgcn_perm(__float_as_uint(y3), __float_as_uint(y2), 0x07060302u); \
    u_[2] = __builtin_amdgcn_perm(__float_as_uint(y5), __float_as_uint(y4), 0x07060302u); \
    u_[3] = __builtin_amdgcn_perm(__float_as_uint(y7), __float_as_uint(y6), 0x07060302u); \
    char* rb_ = ringb + (mw) * RINGSZ;                                         \
    *(uint4v*)(rb_ + wb0) = t_;                                                \
    *(uint4v*)(rb_ + wb1) = u_;                                                \
  } while (0)

// A-frag for rowgroup rg, k-step kk (swizzle: granule ^ rowm)
#define AF(rg, kk)                                                             \
  (*(const bf16x8*)(ringb + mR * RINGSZ + ((rg) * 16 + rowm) * 256 +           \
                    ((((kk) * 4 + g) ^ rowm) << 4)))
#define MQD(ACC, ACCD, rg, kk, FB, FD) do {                                    \
    Frag af_; af_.v = AF(rg, kk);                                              \
    ACC  = __builtin_amdgcn_mfma_f32_16x16x32_bf16(af_.v, FB.v, ACC,  0, 0, 0);\
    ACCD = __builtin_amdgcn_mfma_f32_16x16x32_bf16(af_.v, FD.v, ACCD, 0, 0, 0);\
  } while (0)
#define MQO(ACC, rg, kk, FB) do {                                              \
    Frag af_; af_.v = AF(rg, kk);                                              \
    ACC = __builtin_amdgcn_mfma_f32_16x16x32_bf16(af_.v, FB.v, ACC, 0, 0, 0);  \
  } while (0)

// wave 0: entry [ownB(c)x4, A(c+1)x4]; issue denB(c)x4, ownB(c+1)x4, A(c+2)x4;
// vmcnt(12) drains ownB(c)+A(c+1); vmcnt(8) post-barrier drains denB(c).
#define ITERD(cc, AC0, AC1, AC2, AC3, AN0, AN1, AN2, AN3,                      \
              CO0, CO1, CO2, CO3, NO0, NO1, NO2, NO3) do {                     \
    LOADBD(bd0, cc, 0); LOADBD(bd1, cc, 1);                                    \
    LOADBD(bd2, cc, 2); LOADBD(bd3, cc, 3);                                    \
    { const int cb_ = ((cc) + 1 < NIT) ? (cc) + 1 : NIT - 1;                   \
      LOADBO(NO0, cb_, 0); LOADBO(NO1, cb_, 1);                                \
      LOADBO(NO2, cb_, 2); LOADBO(NO3, cb_, 3); }                              \
    { const int ca_ = ((cc) + 2 < NIT) ? (cc) + 2 : NIT - 1;                   \
      LOADA4(AN0, AN1, AN2, AN3, ca_); }                                       \
    asm volatile("s_waitcnt vmcnt(12)" ::: "memory");                          \
    __builtin_amdgcn_sched_barrier(0);                                         \
    EXPP(AC0, AC1, AC2, AC3, mW);                                              \
    asm volatile("s_waitcnt lgkmcnt(0)" ::: "memory");                         \
    __builtin_amdgcn_sched_barrier(0);                                         \
    __builtin_amdgcn_s_barrier();                                              \
    asm volatile("s_waitcnt vmcnt(8)" ::: "memory");                           \
    __builtin_amdgcn_sched_barrier(0);                                         \
    MQD(acc0, accd0, 0, 0, CO0, bd0); MQD(acc1, accd1, 1, 0, CO0, bd0);        \
    MQD(acc2, accd2, 2, 0, CO0, bd0); MQD(acc3, accd3, 3, 0, CO0, bd0);        \
    MQD(acc0, accd0, 0, 1, CO1, bd1); MQD(acc1, accd1, 1, 1, CO1, bd1);        \
    MQD(acc2, accd2, 2, 1, CO1, bd1); MQD(acc3, accd3, 3, 1, CO1, bd1);        \
    MQD(acc0, accd0, 0, 2, CO2, bd2); MQD(acc1, accd1, 1, 2, CO2, bd2);        \
    MQD(acc2, accd2, 2, 2, CO2, bd2); MQD(acc3, accd3, 3, 2, CO2, bd2);        \
    MQD(acc0, accd0, 0, 3, CO3, bd3); MQD(acc1, accd1, 1, 3, CO3, bd3);        \
    MQD(acc2, accd2, 2, 3, CO3, bd3); MQD(acc3, accd3, 3, 3, CO3, bd3);        \
    mR = mW; mW = (mW + 1 == 3) ? 0 : mW + 1;                                  \
  } while (0)
// waves 1..7: entry [ownB(c)x4, A(c+1)x4]; issue ownB(c+1)x4, A(c+2)x4;
// vmcnt(8) drains ownB(c)+A(c+1).
#define ITERO(cc, AC0, AC1, AC2, AC3, AN0, AN1, AN2, AN3,                      \
              CO0, CO1, CO2, CO3, NO0, NO1, NO2, NO3) do {                     \
    { const int cb_ = ((cc) + 1 < NIT) ? (cc) + 1 : NIT - 1;                   \
      LOADBO(NO0, cb_, 0); LOADBO(NO1, cb_, 1);                                \
      LOADBO(NO2, cb_, 2); LOADBO(NO3, cb_, 3); }                              \
    { const int ca_ = ((cc) + 2 < NIT) ? (cc) + 2 : NIT - 1;                   \
      LOADA4(AN0, AN1, AN2, AN3, ca_); }                                       \
    asm volatile("s_waitcnt vmcnt(8)" ::: "memory");                           \
    __builtin_amdgcn_sched_barrier(0);                                         \
    EXPP(AC0, AC1, AC2, AC3, mW);                                              \
    asm volatile("s_waitcnt lgkmcnt(0)" ::: "memory");                         \
    __builtin_amdgcn_sched_barrier(0);                                         \
    __builtin_amdgcn_s_barrier();                                              \
    MQO(acc0, 0, 0, CO0); MQO(acc1, 1, 0, CO0);                                \
    MQO(acc2, 2, 0, CO0); MQO(acc3, 3, 0, CO0);                                \
    MQO(acc0, 0, 1, CO1); MQO(acc1, 1, 1, CO1);                                \
    MQO(acc2, 2, 1, CO1); MQO(acc3, 3, 1, CO1);                                \
    MQO(acc0, 0, 2, CO2); MQO(acc1, 1, 2, CO2);                                \
    MQO(acc2, 2, 2, CO2); MQO(acc3, 3, 2, CO2);                                \
    MQO(acc0, 0, 3, CO3); MQO(acc1, 1, 3, CO3);                                \
    MQO(acc2, 2, 3, CO3); MQO(acc3, 3, 3, CO3);                                \
    mR = mW; mW = (mW + 1 == 3) ? 0 : mW + 1;                                  \
  } while (0)

  if (w == 0) {
    // prologue: [A(0)x4, ownB(0)x4, A(1)x4] = 12; vmcnt(8) drains A(0)
    LOADA4(aXa, aXb, aXc, aXd, 0);
    LOADBO(bo0, 0, 0); LOADBO(bo1, 0, 1); LOADBO(bo2, 0, 2); LOADBO(bo3, 0, 3);
    LOADA4(aYa, aYb, aYc, aYd, 1);
    asm volatile("s_waitcnt vmcnt(8)" ::: "memory");
    __builtin_amdgcn_sched_barrier(0);
    EXPP(aXa, aXb, aXc, aXd, 0);
#pragma unroll 1
    for (int i = 0; i < NIT; i += 2) {
      ITERD(i,     aYa, aYb, aYc, aYd, aXa, aXb, aXc, aXd,
                   bo0, bo1, bo2, bo3, co0, co1, co2, co3);
      ITERD(i + 1, aXa, aXb, aXc, aXd, aYa, aYb, aYc, aYd,
                   co0, co1, co2, co3, bo0, bo1, bo2, bo3);
    }
  } else {
    LOADA4(aXa, aXb, aXc, aXd, 0);
    LOADBO(bo0, 0, 0); LOADBO(bo1, 0, 1); LOADBO(bo2, 0, 2); LOADBO(bo3, 0, 3);
    LOADA4(aYa, aYb, aYc, aYd, 1);
    asm volatile("s_waitcnt vmcnt(8)" ::: "memory");
    __builtin_amdgcn_sched_barrier(0);
    EXPP(aXa, aXb, aXc, aXd, 0);
#pragma unroll 1
    for (int i = 0; i < NIT; i += 2) {
      ITERO(i,     aYa, aYb, aYc, aYd, aXa, aXb, aXc, aXd,
                   bo0, bo1, bo2, bo3, co0, co1, co2, co3);
      ITERO(i + 1, aXa, aXb, aXc, aXd, aYa, aYb, aYc, aYd,
                   co0, co1, co2, co3, bo0, bo1, bo2, bo3);
    }
  }

  // drain in-flight asm loads before epilogue reuses their dest regs
  asm volatile("s_waitcnt vmcnt(0)" ::: "memory");
  __builtin_amdgcn_sched_barrier(0);

  // C/D: row = rg*16 + g*4 + r, col = rowm. Wave w -> output cols w*16+rowm.
  // accd (wave 0) col h = denominator for head h.
  if (NS == 1) {
    if (w == 0 && rowm < NH) {
#pragma unroll
      for (int r = 0; r < 4; ++r) {
        denLds[(     g * 4 + r) * NH + rowm] = accd0[r];
        denLds[(16 + g * 4 + r) * NH + rowm] = accd1[r];
        denLds[(32 + g * 4 + r) * NH + rowm] = accd2[r];
        denLds[(48 + g * 4 + r) * NH + rowm] = accd3[r];
      }
    }
    __syncthreads();
    const int hh = w >> 1;
#pragma unroll
    for (int r = 0; r < 4; ++r) {
      const int rr = g * 4 + r;
      float o;
      o = acc0[r] / denLds[(     rr) * NH + hh];
      out[(size_t)(b0 +      rr) * OUTW + w * 16 + rowm] = o > 0.f ? o : 0.f;
      o = acc1[r] / denLds[(16 + rr) * NH + hh];
      out[(size_t)(b0 + 16 + rr) * OUTW + w * 16 + rowm] = o > 0.f ? o : 0.f;
      o = acc2[r] / denLds[(32 + rr) * NH + hh];
      out[(size_t)(b0 + 32 + rr) * OUTW + w * 16 + rowm] = o > 0.f ? o : 0.f;
      o = acc3[r] / denLds[(48 + rr) * NH + hh];
      out[(size_t)(b0 + 48 + rr) * OUTW + w * 16 + rowm] = o > 0.f ? o : 0.f;
    }
  } else {
    float* ob = op + (size_t)s * (N_TOK * OUTW) + (size_t)b0 * OUTW + w * 16 + rowm;
#pragma unroll
    for (int r = 0; r < 4; ++r) {
      const int rr = g * 4 + r;
      ob[(size_t)(     rr) * OUTW] = acc0[r];
      ob[(size_t)(16 + rr) * OUTW] = acc1[r];
      ob[(size_t)(32 + rr) * OUTW] = acc2[r];
      ob[(size_t)(48 + rr) * OUTW] = acc3[r];
    }
    if (w == 0 && rowm < NH) {
#pragma unroll
      for (int r = 0; r < 4; ++r) {
        const int rr = g * 4 + r;
        dp[((size_t)s * N_TOK + b0 +      rr) * NH + rowm] = accd0[r];
        dp[((size_t)s * N_TOK + b0 + 16 + rr) * NH + rowm] = accd1[r];
        dp[((size_t)s * N_TOK + b0 + 32 + rr) * NH + rowm] = accd2[r];
        dp[((size_t)s * N_TOK + b0 + 48 + rr) * NH + rowm] = accd3[r];
      }
    }
  }
#undef LOADA4
#undef LOADBO
#undef LOADBD
#undef EXPP
#undef AF
#undef MQD
#undef MQO
#undef ITERD
#undef ITERO
}

// ---------- Kernel 3: combine splits, divide, relu ----------
__global__ __launch_bounds__(256) void comb_kernel(
    const float* __restrict__ op, const float* __restrict__ dp,
    float* __restrict__ out, int NS) {
  const int idx4 = blockIdx.x * 256 + threadIdx.x;
  const int eb = idx4 >> 5;
  const int h  = ((idx4 << 2) & 127) >> 5;
  float4 o; o.x = 0.f; o.y = 0.f; o.z = 0.f; o.w = 0.f;
  float d = 0.f;
  for (int s2 = 0; s2 < NS; ++s2) {
    float4 vv = *(const float4*)(op + (size_t)s2 * (N_TOK * OUTW) + (size_t)idx4 * 4);
    o.x += vv.x; o.y += vv.y; o.z += vv.z; o.w += vv.w;
    d += dp[((size_t)s2 * N_TOK + eb) * NH + h];
  }
  const float r = 1.f / d;
  float4 res;
  res.x = fmaxf(o.x * r, 0.f);
  res.y = fmaxf(o.y * r, 0.f);
  res.z = fmaxf(o.z * r, 0.f);
  res.w = fmaxf(o.w * r, 0.f);
  *(float4*)(out + (size_t)idx4 * 4) = res;
}

extern "C" void kernel_launch(void* const* d_in, const int* in_sizes, int n_in,
                              void* d_out, int out_size, void* d_ws, size_t ws_size,
                              hipStream_t stream) {
  // inputs: 0=X(unused) 1=G 2=A 3=W 4=b 5=a_src(unused) 6=a_dst 7=att_b(unused)
  const float* G     = (const float*)d_in[1];
  const float* A     = (const float*)d_in[2];
  const float* W     = (const float*)d_in[3];
  const float* bias  = (const float*)d_in[4];
  const float* a_dst = (const float*)d_in[6];

  char* ws = (char*)d_ws;
  const size_t PBsz = (size_t)128 * 9 * 1024;  // 1,179,648 B
  const size_t per_split = (size_t)N_TOK * OUTW * 4 + (size_t)N_TOK * NH * 4;

  unsigned short* PB = (unsigned short*)ws;
  float* op = (float*)(ws + PBsz);
  float* outp = (float*)d_out;

  prep_kernel<<<N_TOK / NT, 128, 0, stream>>>(G, W, bias, a_dst, PB);
  if (ws_size >= PBsz + 8 * per_split) {
    float* dp = (float*)(ws + PBsz + 8 * (size_t)N_TOK * OUTW * 4);
    attn_kernel<8><<<(N_TOK / BT) * 8, 512, 0, stream>>>(A, PB, op, dp, nullptr);
    comb_kernel<<<(N_TOK * OUTW / 4) / 256, 256, 0, stream>>>(op, dp, outp, 8);
  } else if (ws_size >= PBsz + 4 * per_split) {
    float* dp = (float*)(ws + PBsz + 4 * (size_t)N_TOK * OUTW * 4);
    attn_kernel<4><<<(N_TOK / BT) * 4, 512, 0, stream>>>(A, PB, op, dp, nullptr);
    comb_kernel<<<(N_TOK * OUTW / 4) / 256, 256, 0, stream>>>(op, dp, outp, 4);
  } else if (ws_size >= PBsz + 2 * per_split) {
    float* dp = (float*)(ws + PBsz + 2 * (size_t)N_TOK * OUTW * 4);
    attn_kernel<2><<<(N_TOK / BT) * 2, 512, 0, stream>>>(A, PB, op, dp, nullptr);
    comb_kernel<<<(N_TOK * OUTW / 4) / 256, 256, 0, stream>>>(op, dp, outp, 2);
  } else {
    attn_kernel<1><<<N_TOK / BT, 512, 0, stream>>>(A, PB, nullptr, nullptr, outp);
  }
}

// Round 12
// 31.763 us; speedup vs baseline: 1.0767x; 1.0767x over previous
//
#include <hip/hip_runtime.h>
#include <stdint.h>

#define N_TOK 4096
#define D_IN  64
#define NF    32
#define NH    4
#define OUTW  (NH * NF)        // 128
#define NT    8
#define CHUNK 128              // n per chunk (4 k-steps of 32)
#define BT    32               // rows per block (2 rowgroups of 16)

typedef float        f32x4  __attribute__((ext_vector_type(4)));
typedef unsigned int uint4v __attribute__((ext_vector_type(4)));
typedef __bf16       bf16x8 __attribute__((ext_vector_type(8)));

union Frag { uint4v u; bf16x8 v; };

static __device__ __forceinline__ unsigned short f2bf_rne(float x) {
  unsigned u = __float_as_uint(x);
  u += 0x7fffu + ((u >> 16) & 1u);
  return (unsigned short)(u >> 16);
}
static __device__ __forceinline__ float bflo(unsigned x) {
  return __uint_as_float(x << 16);
}
static __device__ __forceinline__ float bfhi(unsigned x) {
  return __uint_as_float(x & 0xffff0000u);
}

// ---------- Kernel 1: PB = WG2 fragment-packed (8 sets), EDH[h][n] ----------
// PB 16-B slot ((t*8 + set)*64 + gq*16 + col): t = n>>5, gq = (n>>3)&3,
// set = h*2 + fhalf, col = f&15, 8 bf16 (j = n&7). Total 1 MB.
__global__ __launch_bounds__(128) void prep_kernel(
    const float* __restrict__ G, const float* __restrict__ W,
    const float* __restrict__ bias, const float* __restrict__ a_dst,
    unsigned short* __restrict__ EDH, unsigned short* __restrict__ PB) {
  __shared__ float gs[NT * D_IN];
  const int tid = threadIdx.x;
  const int n0  = blockIdx.x * NT;
  {
    const float4* src = (const float4*)(G + (size_t)n0 * D_IN);
    float4* dst = (float4*)gs;
    dst[tid] = src[tid];
  }
  __syncthreads();
  const int h = tid >> 5, f = tid & 31;
  float acc[NT];
  const float bb = bias[h * NF + f];
#pragma unroll
  for (int k = 0; k < NT; ++k) acc[k] = bb;
#pragma unroll
  for (int i = 0; i < D_IN; ++i) {
    const float wv = W[(h * D_IN + i) * NF + f];
#pragma unroll
    for (int k = 0; k < NT; ++k) acc[k] = fmaf(gs[k * D_IN + i], wv, acc[k]);
  }
  const float ad = a_dst[h * NF + f];
  float ev[NT];
#pragma unroll
  for (int k = 0; k < NT; ++k) {
    float s = acc[k] * ad;
    s += __shfl_xor(s, 1);  s += __shfl_xor(s, 2);  s += __shfl_xor(s, 4);
    s += __shfl_xor(s, 8);  s += __shfl_xor(s, 16);
    ev[k] = __expf(s);
  }
  const int t   = n0 >> 5;
  const int gq  = (n0 >> 3) & 3;
  const int set = (h << 1) | (f >> 4);
  const int col = f & 15;
  union { uint4 u4; unsigned short us[8]; } pk;
#pragma unroll
  for (int k = 0; k < NT; ++k) pk.us[k] = f2bf_rne(acc[k] * ev[k]);
  *(uint4*)(PB + (size_t)((((t * 8 + set) << 6) + (gq << 4) + col)) * 8) = pk.u4;
  if (f == 0) {
    union { uint4 u4; unsigned short us[8]; } pe;
#pragma unroll
    for (int k = 0; k < NT; ++k) pe.us[k] = f2bf_rne(ev[k]);
    *(uint4*)&EDH[(size_t)h * N_TOK + n0] = pe.u4;
  }
}

// ---------- Kernel 2: r9 skeleton, den via staging-side VALU (uniform waves) -
// grid = (4096/32)*NS, 512 thr (8 waves = sets). Per iter (uniform all waves):
// issue B(c+1)x4 + A(c+2)x2; vmcnt(6); exp + 32 den-FMA vs LDS EDt (broadcast
// reads, conflict-free) + pack + swizzled ring write; lgkm; barrier; 8 MFMA.
template <int NS>
__global__ __launch_bounds__(512) void attn_kernel(
    const float* __restrict__ A, const unsigned short* __restrict__ EDH,
    const unsigned short* __restrict__ PB, float* __restrict__ op,
    float* __restrict__ dp, float* __restrict__ out) {
  constexpr int NHALF  = N_TOK / NS;
  constexpr int NIT    = NHALF / CHUNK;
  constexpr int RINGSZ = BT * CHUNK * 2;                         // 8192 B
  __shared__ __align__(16) unsigned short ring[3 * BT * CHUNK];  // 24 KB
  __shared__ __align__(16) unsigned short EDt[NH * NHALF];       // 8/16/32 KB
  __shared__ float denLds[BT * NH];                              // 512 B
  char* ringb = (char*)ring;

  const int tid  = threadIdx.x;
  const int lane = tid & 63;
  const int w    = tid >> 6;
  const int bid  = blockIdx.x;
  const int s    = bid & (NS - 1);
  const int b0   = (bid / NS) * BT;

  // staging coords: 512 thr = 32 rows x 16 col-groups of 8
  const int srow = tid >> 4, tp = tid & 15;
  const float* abase = A + (size_t)(b0 + srow) * N_TOK + s * NHALF + tp * 8;
  const int wb0 = srow * 256 + ((tp ^ (srow & 15)) << 4);  // swizzled 16-B slot

  // MFMA frag coords
  const int rowm = lane & 15, g = lane >> 4;
  const char* pbb  = (const char*)PB + (size_t)s * (NHALF / 32) * 8192;
  const char* pown = pbb + (((w << 6) + lane) << 4);

  { // EDH[h][s*NHALF ..] -> EDt[h][0..NHALF)
    const uint4* src = (const uint4*)EDH;
    uint4* dst = (uint4*)EDt;
    constexpr int tot = NH * NHALF / 8;
#pragma unroll 1
    for (int i = tid; i < tot; i += 512) {
      const int hh = i / (NHALF / 8), k = i % (NHALF / 8);
      dst[i] = src[hh * (N_TOK / 8) + s * (NHALF / 8) + k];
    }
  }
  __syncthreads();

  f32x4 acc0 = {0.f, 0.f, 0.f, 0.f}, acc1 = {0.f, 0.f, 0.f, 0.f};
  f32x4 dsum = {0.f, 0.f, 0.f, 0.f};
  f32x4 aXa, aXb, aYa, aYb;
  Frag bo0, bo1, bo2, bo3, co0, co1, co2, co3;
  int mR = 0, mW = 1;

#define LOADA2(d0, d1, cc) do {                                                \
    const float* ap_ = abase + (size_t)(cc) * CHUNK;                           \
    asm volatile("global_load_dwordx4 %0, %1, off"                            \
                 : "=v"(d0) : "v"(ap_) : "memory");                            \
    asm volatile("global_load_dwordx4 %0, %1, off"                            \
                 : "=v"(d1) : "v"(ap_ + 4) : "memory");                        \
  } while (0)
#define LOADB(fr, cc, kk)                                                      \
  asm volatile("global_load_dwordx4 %0, %1, off"                              \
               : "=v"(fr.u)                                                    \
               : "v"(pown + (size_t)((cc) * 4 + (kk)) * 8192) : "memory")

// exp + (guarded) den-FMA vs EDt broadcast reads + bf16 pack + swizzled write
#define EXPP(AV0, AV1, cchunk, mw) do {                                        \
    float x0 = __expf(-AV0[0]), x1 = __expf(-AV0[1]);                          \
    float x2 = __expf(-AV0[2]), x3 = __expf(-AV0[3]);                          \
    float x4 = __expf(-AV1[0]), x5 = __expf(-AV1[1]);                          \
    float x6 = __expf(-AV1[2]), x7 = __expf(-AV1[3]);                          \
    if ((cchunk) < NIT) {                                                      \
      const int eo_ = (cchunk) * CHUNK + tp * 8;                               \
      uint4v e0_ = *(const uint4v*)&EDt[0 * NHALF + eo_];                      \
      uint4v e1_ = *(const uint4v*)&EDt[1 * NHALF + eo_];                      \
      uint4v e2_ = *(const uint4v*)&EDt[2 * NHALF + eo_];                      \
      uint4v e3_ = *(const uint4v*)&EDt[3 * NHALF + eo_];                      \
      dsum[0] = fmaf(x0, bflo(e0_[0]), dsum[0]);                               \
      dsum[0] = fmaf(x1, bfhi(e0_[0]), dsum[0]);                               \
      dsum[0] = fmaf(x2, bflo(e0_[1]), dsum[0]);                               \
      dsum[0] = fmaf(x3, bfhi(e0_[1]), dsum[0]);                               \
      dsum[0] = fmaf(x4, bflo(e0_[2]), dsum[0]);                               \
      dsum[0] = fmaf(x5, bfhi(e0_[2]), dsum[0]);                               \
      dsum[0] = fmaf(x6, bflo(e0_[3]), dsum[0]);                               \
      dsum[0] = fmaf(x7, bfhi(e0_[3]), dsum[0]);                               \
      dsum[1] = fmaf(x0, bflo(e1_[0]), dsum[1]);                               \
      dsum[1] = fmaf(x1, bfhi(e1_[0]), dsum[1]);                               \
      dsum[1] = fmaf(x2, bflo(e1_[1]), dsum[1]);                               \
      dsum[1] = fmaf(x3, bfhi(e1_[1]), dsum[1]);                               \
      dsum[1] = fmaf(x4, bflo(e1_[2]), dsum[1]);                               \
      dsum[1] = fmaf(x5, bfhi(e1_[2]), dsum[1]);                               \
      dsum[1] = fmaf(x6, bflo(e1_[3]), dsum[1]);                               \
      dsum[1] = fmaf(x7, bfhi(e1_[3]), dsum[1]);                               \
      dsum[2] = fmaf(x0, bflo(e2_[0]), dsum[2]);                               \
      dsum[2] = fmaf(x1, bfhi(e2_[0]), dsum[2]);                               \
      dsum[2] = fmaf(x2, bflo(e2_[1]), dsum[2]);                               \
      dsum[2] = fmaf(x3, bfhi(e2_[1]), dsum[2]);                               \
      dsum[2] = fmaf(x4, bflo(e2_[2]), dsum[2]);                               \
      dsum[2] = fmaf(x5, bfhi(e2_[2]), dsum[2]);                               \
      dsum[2] = fmaf(x6, bflo(e2_[3]), dsum[2]);                               \
      dsum[2] = fmaf(x7, bfhi(e2_[3]), dsum[2]);                               \
      dsum[3] = fmaf(x0, bflo(e3_[0]), dsum[3]);                               \
      dsum[3] = fmaf(x1, bfhi(e3_[0]), dsum[3]);                               \
      dsum[3] = fmaf(x2, bflo(e3_[1]), dsum[3]);                               \
      dsum[3] = fmaf(x3, bfhi(e3_[1]), dsum[3]);                               \
      dsum[3] = fmaf(x4, bflo(e3_[2]), dsum[3]);                               \
      dsum[3] = fmaf(x5, bfhi(e3_[2]), dsum[3]);                               \
      dsum[3] = fmaf(x6, bflo(e3_[3]), dsum[3]);                               \
      dsum[3] = fmaf(x7, bfhi(e3_[3]), dsum[3]);                               \
    }                                                                          \
    uint4v t_;                                                                 \
    t_[0] = __builtin_amdgcn_perm(__float_as_uint(x1), __float_as_uint(x0), 0x07060302u); \
    t_[1] = __builtin_amdgcn_perm(__float_as_uint(x3), __float_as_uint(x2), 0x07060302u); \
    t_[2] = __builtin_amdgcn_perm(__float_as_uint(x5), __float_as_uint(x4), 0x07060302u); \
    t_[3] = __builtin_amdgcn_perm(__float_as_uint(x7), __float_as_uint(x6), 0x07060302u); \
    *(uint4v*)(ringb + (mw) * RINGSZ + wb0) = t_;                              \
  } while (0)

#define MSTEP(rg, kk, FB) do {                                                 \
    Frag af_;                                                                  \
    af_.v = *(const bf16x8*)(ringb + mR * RINGSZ + ((rg) * 16 + rowm) * 256 +  \
                             ((((kk) * 4 + g) ^ rowm) << 4));                  \
    if ((rg) == 0)                                                             \
      acc0 = __builtin_amdgcn_mfma_f32_16x16x32_bf16(af_.v, FB.v, acc0, 0, 0, 0); \
    else                                                                       \
      acc1 = __builtin_amdgcn_mfma_f32_16x16x32_bf16(af_.v, FB.v, acc1, 0, 0, 0); \
  } while (0)

// uniform: entry [B(c)x4, A(c+1)x2] = 6; issue B(c+1)x4, A(c+2)x2; vmcnt(6)
// drains B(c)+A(c+1), keeps B(c+1)+A(c+2) in flight.
#define ITER(cc, AC0, AC1, AN0, AN1, CO0, CO1, CO2, CO3,                       \
             NO0, NO1, NO2, NO3) do {                                          \
    { const int cb_ = ((cc) + 1 < NIT) ? (cc) + 1 : NIT - 1;                   \
      LOADB(NO0, cb_, 0); LOADB(NO1, cb_, 1);                                  \
      LOADB(NO2, cb_, 2); LOADB(NO3, cb_, 3); }                                \
    { const int ca_ = ((cc) + 2 < NIT) ? (cc) + 2 : NIT - 1;                   \
      LOADA2(AN0, AN1, ca_); }                                                 \
    asm volatile("s_waitcnt vmcnt(6)" ::: "memory");                           \
    __builtin_amdgcn_sched_barrier(0);                                         \
    EXPP(AC0, AC1, (cc) + 1, mW);                                              \
    asm volatile("s_waitcnt lgkmcnt(0)" ::: "memory");                         \
    __builtin_amdgcn_sched_barrier(0);                                         \
    __builtin_amdgcn_s_barrier();                                              \
    MSTEP(0, 0, CO0); MSTEP(1, 0, CO0);                                        \
    MSTEP(0, 1, CO1); MSTEP(1, 1, CO1);                                        \
    MSTEP(0, 2, CO2); MSTEP(1, 2, CO2);                                        \
    MSTEP(0, 3, CO3); MSTEP(1, 3, CO3);                                        \
    mR = mW; mW = (mW + 1 == 3) ? 0 : mW + 1;                                  \
  } while (0)

  // prologue: queue [A(0)x2, B(0)x4, A(1)x2] = 8; vmcnt(6) drains A(0)
  LOADA2(aXa, aXb, 0);
  LOADB(bo0, 0, 0); LOADB(bo1, 0, 1); LOADB(bo2, 0, 2); LOADB(bo3, 0, 3);
  LOADA2(aYa, aYb, 1);
  asm volatile("s_waitcnt vmcnt(6)" ::: "memory");
  __builtin_amdgcn_sched_barrier(0);
  EXPP(aXa, aXb, 0, 0);

#pragma unroll 1
  for (int i = 0; i < NIT; i += 2) {
    ITER(i,     aYa, aYb, aXa, aXb, bo0, bo1, bo2, bo3, co0, co1, co2, co3);
    ITER(i + 1, aXa, aXb, aYa, aYb, co0, co1, co2, co3, bo0, bo1, bo2, bo3);
  }

  // drain in-flight asm loads before epilogue reuses their dest regs
  asm volatile("s_waitcnt vmcnt(0)" ::: "memory");
  __builtin_amdgcn_sched_barrier(0);

  // denominator: reduce over the 16 threads (tp) sharing a row
#pragma unroll
  for (int m = 1; m <= 8; m <<= 1) {
    dsum[0] += __shfl_xor(dsum[0], m);
    dsum[1] += __shfl_xor(dsum[1], m);
    dsum[2] += __shfl_xor(dsum[2], m);
    dsum[3] += __shfl_xor(dsum[3], m);
  }

  // C/D: row = rg*16 + g*4 + r, col = rowm. Wave w -> output cols w*16+rowm.
  if (NS == 1) {
    if (tp == 0) {
      float4 dv; dv.x = dsum[0]; dv.y = dsum[1]; dv.z = dsum[2]; dv.w = dsum[3];
      *(float4*)&denLds[srow * NH] = dv;
    }
    __syncthreads();
    const int hh = w >> 1;
#pragma unroll
    for (int r = 0; r < 4; ++r) {
      const int rr = g * 4 + r;
      float o;
      o = acc0[r] / denLds[rr * NH + hh];
      out[(size_t)(b0 + rr) * OUTW + w * 16 + rowm] = o > 0.f ? o : 0.f;
      o = acc1[r] / denLds[(16 + rr) * NH + hh];
      out[(size_t)(b0 + 16 + rr) * OUTW + w * 16 + rowm] = o > 0.f ? o : 0.f;
    }
  } else {
    if (tp == 0) {
      float4 dv; dv.x = dsum[0]; dv.y = dsum[1]; dv.z = dsum[2]; dv.w = dsum[3];
      *(float4*)&dp[((size_t)s * N_TOK + b0 + srow) * NH] = dv;
    }
    float* ob = op + (size_t)s * (N_TOK * OUTW) + (size_t)b0 * OUTW + w * 16 + rowm;
#pragma unroll
    for (int r = 0; r < 4; ++r) {
      const int rr = g * 4 + r;
      ob[(size_t)rr * OUTW]        = acc0[r];
      ob[(size_t)(16 + rr) * OUTW] = acc1[r];
    }
  }
#undef LOADA2
#undef LOADB
#undef EXPP
#undef MSTEP
#undef ITER
}

// ---------- Kernel 3: combine splits, divide, relu ----------
__global__ __launch_bounds__(256) void comb_kernel(
    const float* __restrict__ op, const float* __restrict__ dp,
    float* __restrict__ out, int NS) {
  const int idx4 = blockIdx.x * 256 + threadIdx.x;
  const int eb = idx4 >> 5;
  const int h  = ((idx4 << 2) & 127) >> 5;
  float4 o; o.x = 0.f; o.y = 0.f; o.z = 0.f; o.w = 0.f;
  float d = 0.f;
  for (int s2 = 0; s2 < NS; ++s2) {
    float4 vv = *(const float4*)(op + (size_t)s2 * (N_TOK * OUTW) + (size_t)idx4 * 4);
    o.x += vv.x; o.y += vv.y; o.z += vv.z; o.w += vv.w;
    d += dp[((size_t)s2 * N_TOK + eb) * NH + h];
  }
  const float r = 1.f / d;
  float4 res;
  res.x = fmaxf(o.x * r, 0.f);
  res.y = fmaxf(o.y * r, 0.f);
  res.z = fmaxf(o.z * r, 0.f);
  res.w = fmaxf(o.w * r, 0.f);
  *(float4*)(out + (size_t)idx4 * 4) = res;
}

extern "C" void kernel_launch(void* const* d_in, const int* in_sizes, int n_in,
                              void* d_out, int out_size, void* d_ws, size_t ws_size,
                              hipStream_t stream) {
  // inputs: 0=X(unused) 1=G 2=A 3=W 4=b 5=a_src(unused) 6=a_dst 7=att_b(unused)
  const float* G     = (const float*)d_in[1];
  const float* A     = (const float*)d_in[2];
  const float* W     = (const float*)d_in[3];
  const float* bias  = (const float*)d_in[4];
  const float* a_dst = (const float*)d_in[6];

  char* ws = (char*)d_ws;
  const size_t PBsz = (size_t)128 * 8 * 1024;   // 1 MB
  const size_t EDsz = (size_t)N_TOK * NH * 2;   // 32 KB
  const size_t base = PBsz + EDsz;
  const size_t per_split = (size_t)N_TOK * OUTW * 4 + (size_t)N_TOK * NH * 4;

  unsigned short* PB  = (unsigned short*)ws;
  unsigned short* EDH = (unsigned short*)(ws + PBsz);
  float* op = (float*)(ws + base);
  float* outp = (float*)d_out;

  prep_kernel<<<N_TOK / NT, 128, 0, stream>>>(G, W, bias, a_dst, EDH, PB);
  if (ws_size >= base + 4 * per_split) {
    float* dp = (float*)(ws + base + 4 * (size_t)N_TOK * OUTW * 4);
    attn_kernel<4><<<(N_TOK / BT) * 4, 512, 0, stream>>>(A, EDH, PB, op, dp, nullptr);
    comb_kernel<<<(N_TOK * OUTW / 4) / 256, 256, 0, stream>>>(op, dp, outp, 4);
  } else if (ws_size >= base + 2 * per_split) {
    float* dp = (float*)(ws + base + 2 * (size_t)N_TOK * OUTW * 4);
    attn_kernel<2><<<(N_TOK / BT) * 2, 512, 0, stream>>>(A, EDH, PB, op, dp, nullptr);
    comb_kernel<<<(N_TOK * OUTW / 4) / 256, 256, 0, stream>>>(op, dp, outp, 2);
  } else {
    attn_kernel<1><<<N_TOK / BT, 512, 0, stream>>>(A, EDH, PB, nullptr, nullptr, outp);
  }
}